// Round 1
// baseline (260.155 us; speedup 1.0000x reference)
//
#include <hip/hip_runtime.h>
#include <cstdint>
#include <cstddef>

typedef int int32x4 __attribute__((ext_vector_type(4)));

#define AS1 __attribute__((address_space(1)))
#define AS3 __attribute__((address_space(3)))

__device__ __forceinline__ void gload_lds16(const void* g, void* l) {
    __builtin_amdgcn_global_load_lds((const AS1 void*)g, (AS3 void*)l, 16, 0, 0);
}

// ---------------------------------------------------------------------------
// Kernel 1: x (fp32, integer-valued int8 range) -> A8 (int8), plus row sums rs
// One block per row of 4096 elements. 256 threads x 4 float4 each.
// ---------------------------------------------------------------------------
__global__ __launch_bounds__(256) void quant_x(const float* __restrict__ x,
                                               signed char* __restrict__ A8,
                                               int* __restrict__ rs) {
    const int row = blockIdx.x;
    const int t = threadIdx.x;
    const float4* xr = (const float4*)(x + (size_t)row * 4096);
    char4* ar = (char4*)(A8 + (size_t)row * 4096);
    int s = 0;
#pragma unroll
    for (int i = 0; i < 4; i++) {
        const int idx = i * 256 + t;
        float4 v = xr[idx];
        int a0 = (int)v.x, a1 = (int)v.y, a2 = (int)v.z, a3 = (int)v.w;
        s += a0 + a1 + a2 + a3;
        char4 c;
        c.x = (signed char)a0; c.y = (signed char)a1;
        c.z = (signed char)a2; c.w = (signed char)a3;
        ar[idx] = c;
    }
    // wave reduce (width 64), then cross-wave via LDS
#pragma unroll
    for (int off = 32; off > 0; off >>= 1) s += __shfl_down(s, off);
    __shared__ int wsum[4];
    if ((t & 63) == 0) wsum[t >> 6] = s;
    __syncthreads();
    if (t == 0) rs[row] = wsum[0] + wsum[1] + wsum[2] + wsum[3];
}

// ---------------------------------------------------------------------------
// Kernel 2: y (fp32, integer-valued uint8 range) -> B8T (int8, TRANSPOSED:
// B8T[n*4096+k] = y[k*4096+n] - 128). 64x64 tiles through LDS.
// Grid (N/64, K/64), 256 threads.
// ---------------------------------------------------------------------------
__global__ __launch_bounds__(256) void quant_y(const float* __restrict__ y,
                                               signed char* __restrict__ B8T) {
    __shared__ signed char tile[64][68];  // +4 pad
    const int nt = blockIdx.x * 64;
    const int kt = blockIdx.y * 64;
    const int t = threadIdx.x;
    const int r0 = t >> 4;         // 0..15
    const int c4 = (t & 15) * 4;   // 0..60
#pragma unroll
    for (int i = 0; i < 4; i++) {
        const int r = i * 16 + r0;  // k within tile
        float4 v = *(const float4*)(y + (size_t)(kt + r) * 4096 + nt + c4);
        char4 c;
        c.x = (signed char)((int)v.x - 128);
        c.y = (signed char)((int)v.y - 128);
        c.z = (signed char)((int)v.z - 128);
        c.w = (signed char)((int)v.w - 128);
        *(char4*)&tile[r][c4] = c;
    }
    __syncthreads();
#pragma unroll
    for (int i = 0; i < 4; i++) {
        const int n = i * 16 + r0;  // n within tile (output row)
        char4 o;
        o.x = tile[c4 + 0][n];
        o.y = tile[c4 + 1][n];
        o.z = tile[c4 + 2][n];
        o.w = tile[c4 + 3][n];
        *(char4*)(B8T + (size_t)(nt + n) * 4096 + kt + c4) = o;
    }
}

// ---------------------------------------------------------------------------
// Kernel 3: sy[n] = sum_k B8T[n][k]  (one block per n-row)
// ---------------------------------------------------------------------------
__global__ __launch_bounds__(256) void colsum(const signed char* __restrict__ B8T,
                                              int* __restrict__ sy) {
    const int n = blockIdx.x;
    const int t = threadIdx.x;
    const char4* rp = (const char4*)(B8T + (size_t)n * 4096);
    int s = 0;
#pragma unroll
    for (int i = 0; i < 4; i++) {
        char4 c = rp[i * 256 + t];
        s += (int)c.x + (int)c.y + (int)c.z + (int)c.w;
    }
#pragma unroll
    for (int off = 32; off > 0; off >>= 1) s += __shfl_down(s, off);
    __shared__ int wsum[4];
    if ((t & 63) == 0) wsum[t >> 6] = s;
    __syncthreads();
    if (t == 0) sy[n] = wsum[0] + wsum[1] + wsum[2] + wsum[3];
}

// ---------------------------------------------------------------------------
// Kernel 4: int8 GEMM, m97 structure. 128x128 block tile, BK=64.
// 4 waves in 2x2, each wave 4x4 grid of 16x16x64 i8 MFMAs.
// A8: M-major M x K int8.  B8T: N-major N x K int8 (so B-frag is contiguous).
// Epilogue: C = 7.5e-4 * (P - 32*rs[m] + 66*sy[n] - 8650752)
// ---------------------------------------------------------------------------
__global__ __launch_bounds__(256) void gemm_i8(const signed char* __restrict__ A8,
                                               const signed char* __restrict__ B8T,
                                               const int* __restrict__ rs,
                                               const int* __restrict__ sy,
                                               float* __restrict__ C) {
    __shared__ __align__(16) signed char As[128 * 64];  // 8 KB
    __shared__ __align__(16) signed char Bs[128 * 64];  // 8 KB
    const int tid = threadIdx.x;
    const int bm = blockIdx.y * 128;
    const int bn = blockIdx.x * 128;
    const int lane = tid & 63;
    const int wave = tid >> 6;
    const int wm = (wave >> 1) * 64;
    const int wn = (wave & 1) * 64;
    const int r16 = lane & 15;
    const int q = lane >> 4;

    int32x4 acc[4][4] = {};

    // staging: chunk c in 0..511 -> LDS offset c*16, row c>>2, kbyte (c&3)*16
    const size_t arow  = (size_t)(bm + (tid >> 2)) * 4096 + (tid & 3) * 16;
    const size_t brow  = (size_t)(bn + (tid >> 2)) * 4096 + (tid & 3) * 16;
    const size_t arow2 = arow + (size_t)64 * 4096;
    const size_t brow2 = brow + (size_t)64 * 4096;
    signed char* a_dst = As + tid * 16;
    signed char* b_dst = Bs + tid * 16;

    for (int kt = 0; kt < 4096; kt += 64) {
        gload_lds16(A8 + arow + kt, a_dst);
        gload_lds16(A8 + arow2 + kt, a_dst + 4096);
        gload_lds16(B8T + brow + kt, b_dst);
        gload_lds16(B8T + brow2 + kt, b_dst + 4096);
        __syncthreads();

        int32x4 af[4], bf[4];
#pragma unroll
        for (int i = 0; i < 4; i++)
            af[i] = *(const int32x4*)(As + (wm + i * 16 + r16) * 64 + q * 16);
#pragma unroll
        for (int j = 0; j < 4; j++)
            bf[j] = *(const int32x4*)(Bs + (wn + j * 16 + r16) * 64 + q * 16);

#pragma unroll
        for (int i = 0; i < 4; i++)
#pragma unroll
            for (int j = 0; j < 4; j++)
                acc[i][j] = __builtin_amdgcn_mfma_i32_16x16x64_i8(af[i], bf[j], acc[i][j], 0, 0, 0);
        __syncthreads();
    }

    // Epilogue. C/D layout (dtype-independent, m89-verified):
    // col = lane&15, row = (lane>>4)*4 + reg
#pragma unroll
    for (int i = 0; i < 4; i++) {
#pragma unroll
        for (int r = 0; r < 4; r++) {
            const int gm = bm + wm + i * 16 + q * 4 + r;
            const int rcorr = -32 * rs[gm] - 8650752;
#pragma unroll
            for (int j = 0; j < 4; j++) {
                const int gn = bn + wn + j * 16 + r16;
                const int v = acc[i][j][r] + rcorr + 66 * sy[gn];
                C[(size_t)gm * 4096 + gn] = 7.5e-4f * (float)v;
            }
        }
    }
}

// ---------------------------------------------------------------------------
extern "C" void kernel_launch(void* const* d_in, const int* in_sizes, int n_in,
                              void* d_out, int out_size, void* d_ws, size_t ws_size,
                              hipStream_t stream) {
    const float* x = (const float*)d_in[0];  // [4096,4096] int8-valued
    const float* y = (const float*)d_in[1];  // [4096,4096] uint8-valued
    float* out = (float*)d_out;

    char* ws = (char*)d_ws;
    signed char* A8  = (signed char*)ws;                         // 16 MiB
    signed char* B8T = (signed char*)(ws + (16u << 20));         // 16 MiB
    int* rs = (int*)(ws + (32u << 20));                          // 16 KiB
    int* sy = (int*)(ws + (32u << 20) + (16u << 10));            // 16 KiB

    quant_x<<<4096, 256, 0, stream>>>(x, A8, rs);
    quant_y<<<dim3(64, 64), 256, 0, stream>>>(y, B8T);
    colsum<<<4096, 256, 0, stream>>>(B8T, sy);
    gemm_i8<<<dim3(32, 32), 256, 0, stream>>>(A8, B8T, rs, sy, out);
}